// Round 13
// baseline (75.433 us; speedup 1.0000x reference)
//
#include <hip/hip_runtime.h>
#include <math.h>

// MoELoRA dims (fixed by the problem)
#define NTOK   16384      // B*S
#define DDIM   1024
#define NE     8
#define NF     128        // E*G*R down-proj features (f = e*16 + g*8 + r)
#define FP     144        // GEMM1 N: 128 h + 8 logits + 8 zero  (9 MFMA N-tiles)
#define ODIM   1024
#define NOUT   3072
#define SCALE  2.0f
#define TOKB   32         // tokens per block -> 512 blocks (4 waves, 2 blocks/CU)

typedef __attribute__((ext_vector_type(8))) short bf16x8;
typedef __attribute__((ext_vector_type(4))) float f32x4;

// ws layout (bytes)
#define WS_ABT 0                        // bf16 [144][1024]   = 294912 B
#define WS_BBT 294912                   // bf16 [2][1024][64] = 262144 B

// pack two fp32 -> (bf16(a) | bf16(b)<<16), round-to-nearest-even
__device__ inline unsigned f2bf(float a, float b) {
    union { float f; unsigned u; } ua, ub;
    ua.f = a; ub.f = b;
    unsigned x = ua.u + (0x7fffu + ((ua.u >> 16) & 1));
    unsigned y = ub.u + (0x7fffu + ((ub.u >> 16) & 1));
    return (x >> 16) | (y & 0xffff0000u);
}

// ---------------------------------------------------------------------------
// Prep: Abt[f][d] = bf16(concat(A, W_route, 0))   (A is already f-major)
//       Bbt[g][o][er] = bf16(Bw[e][g][o][r]), er = e*8+r
__global__ __launch_bounds__(256) void k_prep(const float* __restrict__ A,
                                              const float* __restrict__ Wr,
                                              const float* __restrict__ Bw,
                                              unsigned short* __restrict__ Abt,
                                              unsigned short* __restrict__ Bbt) {
    const int b = blockIdx.x, t = threadIdx.x;
    if (b < FP) {
        const int col = t * 4;
        float4 v = {0.f, 0.f, 0.f, 0.f};
        if (b < NF)           v = *(const float4*)(A + (size_t)b * DDIM + col);
        else if (b < NF + NE) v = *(const float4*)(Wr + (size_t)(b - NF) * DDIM + col);
        uint2 p; p.x = f2bf(v.x, v.y); p.y = f2bf(v.z, v.w);
        *(uint2*)(Abt + (size_t)b * DDIM + col) = p;
    } else {
        const int idx = (b - FP) * 1024 + t * 4;      // over [2][1024][64]
        const int g = idx >> 16, o = (idx >> 6) & 1023, er = idx & 63;
        const int e = er >> 3, r0 = er & 7;           // r0 in {0,4}
        float4 v = *(const float4*)(Bw + ((size_t)(e * 2 + g) * ODIM + o) * 8 + r0);
        uint2 p; p.x = f2bf(v.x, v.y); p.y = f2bf(v.z, v.w);
        *(uint2*)(Bbt + idx) = p;
    }
}

// ---------------------------------------------------------------------------
// Fused, 32-token tiles, 4 waves, 512 blocks (2/CU). Wave (m,h).
//  phase 1: GEMM1 K-loop, 3-deep counted-vmcnt pipeline. Zero-fill of the
//           dead middle third interleaved (2 float4/thread/step) -- counted
//           waits (9|8) leave next step's loads AND last iter's stores in
//           flight, so zeros stream on the idle write pipe under the
//           read-bound K-loop (unlike R9's vmcnt(0) drain).
//  phase 2: in-reg softmax; wh -> LDS; GEMM2 vs L2-hot Bbt; LDS-transpose
//           epilogue, dense 512B-segment stores over the 1024 GEMM cols.
__global__ __launch_bounds__(256) void k_fused(const float* __restrict__ x,
                                               const unsigned short* __restrict__ Abt,
                                               const unsigned short* __restrict__ Bbt,
                                               float* __restrict__ out) {
    __shared__ __align__(16) char smem[67584];
    unsigned short* xs = (unsigned short*)smem;            // [3][32][64] bf16, swizzled
    unsigned short* ab = (unsigned short*)(smem + 12288);  // [3][144][64] bf16, swizzled
    float* whs = (float*)smem;                             // [32][140] fp32 alias (phase 2)

    const int t    = threadIdx.x;
    const int tokb = blockIdx.x * TOKB;
    const int lane = t & 63, w = t >> 6;
    const int m    = w >> 1, h = w & 1;
    const int l15  = lane & 15, lq = lane >> 4;

    f32x4 acc[5];   // 4 expert N-tiles (nt = 2j+h) + logits (tile 8)
#pragma unroll
    for (int n = 0; n < 5; ++n) acc[n] = (f32x4){0.f, 0.f, 0.f, 0.f};

    // x staging: thread covers token t>>3, 8 consecutive floats at (t&7)*8
    const int xtok = t >> 3;
    const int xc   = t & 7;
    float4 xr[3][2];          // 3 in-flight register sets (static indices)

    auto LDX = [&](int set, int k0) {
        xr[set][0] = *(const float4*)(x + (size_t)(tokb + xtok) * DDIM + k0 + xc * 8);
        xr[set][1] = *(const float4*)(x + (size_t)(tokb + xtok) * DDIM + k0 + xc * 8 + 4);
    };
    auto WRX = [&](int j) {   // write xr[j] -> x buffer j (XOR-swizzled)
        unsigned short* xb = xs + j * (TOKB * 64);
        uint4 p;
        p.x = f2bf(xr[j][0].x, xr[j][0].y); p.y = f2bf(xr[j][0].z, xr[j][0].w);
        p.z = f2bf(xr[j][1].x, xr[j][1].y); p.w = f2bf(xr[j][1].z, xr[j][1].w);
        const int c8 = xc ^ (xtok & 7);
        *(uint4*)(xb + xtok * 64 + c8 * 8) = p;
    };
    // A-tile: 18 KB/step via global_load_lds w16; linear LDS dest, source
    // pre-swizzled so content lands XOR-swizzled (rule #21).
    auto LDA = [&](int buf, int k0) {
        unsigned short* base = ab + buf * (144 * 64);
#pragma unroll
        for (int i = 0; i < 5; ++i) {
            if (i < 4 || t < 128) {                // waves 0,1: 5 ops; waves 2,3: 4
                const int c   = i * 256 + t;
                const int row = c >> 3;
                const int c8  = (c & 7) ^ (row & 7);
                const unsigned short* gp = Abt + (size_t)row * DDIM + k0 + c8 * 8;
                unsigned short* lp = base + (i * 256 + w * 64) * 8;  // wave-uniform
                __builtin_amdgcn_global_load_lds(
                    (const __attribute__((address_space(1))) unsigned int*)gp,
                    (__attribute__((address_space(3))) unsigned int*)lp, 16, 0, 0);
            }
        }
    };

    // ---- prologue: steps 0 and 1 in flight; x for step 0 written ----
    LDX(0, 0);   LDA(0, 0);
    LDX(1, 64);  LDA(1, 64);
    WRX(0);

    // ---- K-loop: counted-vmcnt pipeline, prefetch distance 2 ----
    // FIFO at iter-s wait (steady): [loads(s) 7|6, stores(s-2) 2,
    // loads(s+1) 7|6, stores(s-1) 2]. vmcnt(9|8) leaves the newest
    // loads(s+1)+stores(s-1) in flight; loads(s) (issued ~2 step-times ago)
    // and stores(s-2) are retired -> wait is ~free. Buffer safety as R11.
    const float4 zf4 = {0.f, 0.f, 0.f, 0.f};
#pragma unroll 16
    for (int s = 0; s < 16; ++s) {
        if (s == 15)      asm volatile("s_waitcnt vmcnt(0)" ::: "memory");
        else if (s == 0) {
            if (w < 2)    asm volatile("s_waitcnt vmcnt(7)" ::: "memory");
            else          asm volatile("s_waitcnt vmcnt(6)" ::: "memory");
        } else {
            if (w < 2)    asm volatile("s_waitcnt vmcnt(9)" ::: "memory");
            else          asm volatile("s_waitcnt vmcnt(8)" ::: "memory");
        }
        asm volatile("s_waitcnt lgkmcnt(0)" ::: "memory");   // WRX visible
        __builtin_amdgcn_sched_barrier(0);
        __builtin_amdgcn_s_barrier();
        __builtin_amdgcn_sched_barrier(0);
        if (s + 2 < 16) { LDX((s + 2) % 3, (s + 2) * 64); LDA((s + 2) % 3, (s + 2) * 64); }
        // zero-fill of dead middle third: 2 float4/thread/step on the idle
        // write pipe (8192 float4 = 32 rows x 1024 cols over 16 steps)
        {
            const int j0 = s * 512 + t;
            *(float4*)(out + (size_t)(tokb + (j0 >> 8)) * NOUT + 1024 + (j0 & 255) * 4) = zf4;
            const int j1 = j0 + 256;
            *(float4*)(out + (size_t)(tokb + (j1 >> 8)) * NOUT + 1024 + (j1 & 255) * 4) = zf4;
        }
        __builtin_amdgcn_sched_barrier(0);
        const unsigned short* xb  = xs + (s % 3) * (TOKB * 64);
        const unsigned short* abc = ab + (s % 3) * (144 * 64);
        __builtin_amdgcn_s_setprio(1);
#pragma unroll
        for (int ks = 0; ks < 2; ++ks) {
            const int sw = (((ks << 2) | lq) ^ (l15 & 7)) * 8;
            bf16x8 af = *(const bf16x8*)(xb + (m * 16 + l15) * 64 + sw);
#pragma unroll
            for (int j = 0; j < 4; ++j) {
                const int nt = 2 * j + h;
                bf16x8 bf = *(const bf16x8*)(abc + (nt * 16 + l15) * 64 + sw);
                acc[j] = __builtin_amdgcn_mfma_f32_16x16x32_bf16(af, bf, acc[j], 0, 0, 0);
            }
            bf16x8 bl = *(const bf16x8*)(abc + (8 * 16 + l15) * 64 + sw);
            acc[4] = __builtin_amdgcn_mfma_f32_16x16x32_bf16(af, bl, acc[4], 0, 0, 0);
        }
        __builtin_amdgcn_s_setprio(0);
        if (s + 1 < 16) WRX((s + 1) % 3);   // x data for step s+1 (loaded iter s-1)
    }

    // ---- in-register softmax over experts (logits: acc[4], lanes l15<8) ----
    float mx[4], pv[4], sm[4], rt[4];
#pragma unroll
    for (int r = 0; r < 4; ++r) mx[r] = acc[4][r];
#pragma unroll
    for (int msk = 1; msk <= 4; msk <<= 1)
#pragma unroll
        for (int r = 0; r < 4; ++r) mx[r] = fmaxf(mx[r], __shfl_xor(mx[r], msk, 16));
#pragma unroll
    for (int r = 0; r < 4; ++r) { pv[r] = expf(acc[4][r] - mx[r]); sm[r] = pv[r]; }
#pragma unroll
    for (int msk = 1; msk <= 4; msk <<= 1)
#pragma unroll
        for (int r = 0; r < 4; ++r) sm[r] += __shfl_xor(sm[r], msk, 16);
#pragma unroll
    for (int r = 0; r < 4; ++r) rt[r] = SCALE * pv[r] / sm[r];

    __syncthreads();   // xs/ab dead; whs alias becomes live

    // route-weighted wh -> LDS; wave (m,h) supplies experts {h,h+2,h+4,h+6}
#pragma unroll
    for (int j = 0; j < 4; ++j) {
        const int e = 2 * j + h;
        float rb[4];
#pragma unroll
        for (int r = 0; r < 4; ++r) rb[r] = __shfl(rt[r], e, 16);
#pragma unroll
        for (int r = 0; r < 4; ++r)
            whs[(m * 16 + lq * 4 + r) * 140 + e * 16 + l15] = acc[j][r] * rb[r];
    }
    __syncthreads();   // expert exchange between wave pairs

    // GEMM2 A-fragments (group g=h): lane needs expert e = ks*4+lq, r=0..7
    bf16x8 paf[2];   // [ks]
#pragma unroll
    for (int ks = 0; ks < 2; ++ks) {
        const float* hp = whs + (m * 16 + l15) * 140 + ((ks << 2) | lq) * 16 + (h << 3);
        f32x4 v0 = *(const f32x4*)hp;
        f32x4 v1 = *(const f32x4*)(hp + 4);
        uint4 pk;
        pk.x = f2bf(v0[0], v0[1]); pk.y = f2bf(v0[2], v0[3]);
        pk.z = f2bf(v1[0], v1[1]); pk.w = f2bf(v1[2], v1[3]);
        paf[ks] = *(bf16x8*)&pk;
    }
    __syncthreads();   // whs fully consumed; smem reusable as transpose tiles

    // GEMM2 with LDS-transpose epilogue. Wave (m,h) owns rows m*16..+15 x
    // group h's 1024 GEMM cols (zeros already written in phase 1).
    float* tile = (float*)smem + w * (16 * 132);
    const int erow  = lane >> 5;           // 2 rows per store instr
    const int ec4   = lane & 31;           // 32 float4 = full 128-col chunk
    const int gcolb = h << 11;             // GEMM col base: 0 or 2048
#pragma unroll 1
    for (int cb = 0; cb < 8; ++cb) {
#pragma unroll
        for (int nn = 0; nn < 8; ++nn) {
            const int n = cb * 8 + nn;
            const unsigned short* bp =
                Bbt + ((size_t)(h << 10) + (n << 4) + l15) * 64 + (lq << 3);
            bf16x8 b0 = *(const bf16x8*)bp;
            bf16x8 b1 = *(const bf16x8*)(bp + 32);
            f32x4 c = {0.f, 0.f, 0.f, 0.f};
            c = __builtin_amdgcn_mfma_f32_16x16x32_bf16(paf[0], b0, c, 0, 0, 0);
            c = __builtin_amdgcn_mfma_f32_16x16x32_bf16(paf[1], b1, c, 0, 0, 0);
#pragma unroll
            for (int r = 0; r < 4; ++r)
                tile[(lq * 4 + r) * 132 + nn * 16 + l15] = c[r];
        }
        // wave-private tile: same-wave DS ordering + compiler lgkmcnt waits
#pragma unroll
        for (int j = 0; j < 8; ++j) {
            const int row = j * 2 + erow;
            float4 v = *(const float4*)&tile[row * 132 + ec4 * 4];
            *(float4*)(out + (size_t)(tokb + m * 16 + row) * NOUT
                       + gcolb + cb * 128 + ec4 * 4) = v;
        }
    }
}

// ---------------------------------------------------------------------------
extern "C" void kernel_launch(void* const* d_in, const int* in_sizes, int n_in,
                              void* d_out, int out_size, void* d_ws, size_t ws_size,
                              hipStream_t stream) {
    const float* x  = (const float*)d_in[0];
    const float* Wr = (const float*)d_in[1];
    const float* A  = (const float*)d_in[2];
    const float* Bw = (const float*)d_in[3];
    unsigned short* Abt = (unsigned short*)((char*)d_ws + WS_ABT);
    unsigned short* Bbt = (unsigned short*)((char*)d_ws + WS_BBT);
    float* out = (float*)d_out;

    k_prep <<<FP + 128, 256, 0, stream>>>(A, Wr, Bw, Abt, Bbt);
    k_fused<<<NTOK / TOKB, 256, 0, stream>>>(x, Abt, Bbt, out);
}

// Round 14
// 63.573 us; speedup vs baseline: 1.1865x; 1.1865x over previous
//
#include <hip/hip_runtime.h>
#include <math.h>

// MoELoRA dims (fixed by the problem)
#define NTOK   16384      // B*S
#define DDIM   1024
#define NE     8
#define NF     128        // E*G*R down-proj features (f = e*16 + g*8 + r)
#define FP     144        // GEMM1 N: 128 h + 8 logits + 8 zero  (9 MFMA N-tiles)
#define ODIM   1024
#define NOUT   3072
#define SCALE  2.0f
#define TOKB   32         // tokens per block -> 512 blocks (4 waves, 2 blocks/CU)

typedef __attribute__((ext_vector_type(8))) short bf16x8;
typedef __attribute__((ext_vector_type(4))) float f32x4;

// ws layout (bytes)
#define WS_ABT 0                        // bf16 [144][1024]   = 294912 B
#define WS_BBT 294912                   // bf16 [2][1024][64] = 262144 B

// pack two fp32 -> (bf16(a) | bf16(b)<<16), round-to-nearest-even
__device__ inline unsigned f2bf(float a, float b) {
    union { float f; unsigned u; } ua, ub;
    ua.f = a; ub.f = b;
    unsigned x = ua.u + (0x7fffu + ((ua.u >> 16) & 1));
    unsigned y = ub.u + (0x7fffu + ((ub.u >> 16) & 1));
    return (x >> 16) | (y & 0xffff0000u);
}

// ---------------------------------------------------------------------------
// Prep: Abt[f][d] = bf16(concat(A, W_route, 0))   (A is already f-major)
//       Bbt[g][o][er] = bf16(Bw[e][g][o][r]), er = e*8+r
__global__ __launch_bounds__(256) void k_prep(const float* __restrict__ A,
                                              const float* __restrict__ Wr,
                                              const float* __restrict__ Bw,
                                              unsigned short* __restrict__ Abt,
                                              unsigned short* __restrict__ Bbt) {
    const int b = blockIdx.x, t = threadIdx.x;
    if (b < FP) {
        const int col = t * 4;
        float4 v = {0.f, 0.f, 0.f, 0.f};
        if (b < NF)           v = *(const float4*)(A + (size_t)b * DDIM + col);
        else if (b < NF + NE) v = *(const float4*)(Wr + (size_t)(b - NF) * DDIM + col);
        uint2 p; p.x = f2bf(v.x, v.y); p.y = f2bf(v.z, v.w);
        *(uint2*)(Abt + (size_t)b * DDIM + col) = p;
    } else {
        const int idx = (b - FP) * 1024 + t * 4;      // over [2][1024][64]
        const int g = idx >> 16, o = (idx >> 6) & 1023, er = idx & 63;
        const int e = er >> 3, r0 = er & 7;           // r0 in {0,4}
        float4 v = *(const float4*)(Bw + ((size_t)(e * 2 + g) * ODIM + o) * 8 + r0);
        uint2 p; p.x = f2bf(v.x, v.y); p.y = f2bf(v.z, v.w);
        *(uint2*)(Bbt + idx) = p;
    }
}

// ---------------------------------------------------------------------------
// Fused, 32-token tiles, 4 waves, 512 blocks (2/CU). Wave (m,h).
//  phase 1: GEMM1 K-loop, 3-deep counted-vmcnt pipeline (no stores).
//  phase 2: in-reg softmax; wh -> LDS; GEMM2 vs L2-hot Bbt; PIPELINED
//           LDS-transpose epilogue (double-buffered tiles: store chunk cb-1
//           while computing chunk cb) -> near-continuous store issue.
__global__ __launch_bounds__(256) void k_fused(const float* __restrict__ x,
                                               const unsigned short* __restrict__ Abt,
                                               const unsigned short* __restrict__ Bbt,
                                               float* __restrict__ out) {
    __shared__ __align__(16) char smem[67584];
    unsigned short* xs = (unsigned short*)smem;            // [3][32][64] bf16, swizzled
    unsigned short* ab = (unsigned short*)(smem + 12288);  // [3][144][64] bf16, swizzled
    float* whs = (float*)smem;                             // [32][140] fp32 alias (phase 2)

    const int t    = threadIdx.x;
    const int tokb = blockIdx.x * TOKB;
    const int lane = t & 63, w = t >> 6;
    const int m    = w >> 1, h = w & 1;
    const int l15  = lane & 15, lq = lane >> 4;

    f32x4 acc[5];   // 4 expert N-tiles (nt = 2j+h) + logits (tile 8)
#pragma unroll
    for (int n = 0; n < 5; ++n) acc[n] = (f32x4){0.f, 0.f, 0.f, 0.f};

    // x staging: thread covers token t>>3, 8 consecutive floats at (t&7)*8
    const int xtok = t >> 3;
    const int xc   = t & 7;
    float4 xr[3][2];          // 3 in-flight register sets (static indices)

    auto LDX = [&](int set, int k0) {
        xr[set][0] = *(const float4*)(x + (size_t)(tokb + xtok) * DDIM + k0 + xc * 8);
        xr[set][1] = *(const float4*)(x + (size_t)(tokb + xtok) * DDIM + k0 + xc * 8 + 4);
    };
    auto WRX = [&](int j) {   // write xr[j] -> x buffer j (XOR-swizzled)
        unsigned short* xb = xs + j * (TOKB * 64);
        uint4 p;
        p.x = f2bf(xr[j][0].x, xr[j][0].y); p.y = f2bf(xr[j][0].z, xr[j][0].w);
        p.z = f2bf(xr[j][1].x, xr[j][1].y); p.w = f2bf(xr[j][1].z, xr[j][1].w);
        const int c8 = xc ^ (xtok & 7);
        *(uint4*)(xb + xtok * 64 + c8 * 8) = p;
    };
    // A-tile: 18 KB/step via global_load_lds w16; linear LDS dest, source
    // pre-swizzled so content lands XOR-swizzled (rule #21).
    auto LDA = [&](int buf, int k0) {
        unsigned short* base = ab + buf * (144 * 64);
#pragma unroll
        for (int i = 0; i < 5; ++i) {
            if (i < 4 || t < 128) {                // waves 0,1: 5 ops; waves 2,3: 4
                const int c   = i * 256 + t;
                const int row = c >> 3;
                const int c8  = (c & 7) ^ (row & 7);
                const unsigned short* gp = Abt + (size_t)row * DDIM + k0 + c8 * 8;
                unsigned short* lp = base + (i * 256 + w * 64) * 8;  // wave-uniform
                __builtin_amdgcn_global_load_lds(
                    (const __attribute__((address_space(1))) unsigned int*)gp,
                    (__attribute__((address_space(3))) unsigned int*)lp, 16, 0, 0);
            }
        }
    };

    // ---- prologue: steps 0 and 1 in flight; x for step 0 written ----
    LDX(0, 0);   LDA(0, 0);
    LDX(1, 64);  LDA(1, 64);
    WRX(0);

    // ---- K-loop: counted-vmcnt pipeline, prefetch distance 2 ----
#pragma unroll 16
    for (int s = 0; s < 16; ++s) {
        if (s == 15)    asm volatile("s_waitcnt vmcnt(0)" ::: "memory");
        else if (w < 2) asm volatile("s_waitcnt vmcnt(7)" ::: "memory");
        else            asm volatile("s_waitcnt vmcnt(6)" ::: "memory");
        asm volatile("s_waitcnt lgkmcnt(0)" ::: "memory");   // WRX visible
        __builtin_amdgcn_sched_barrier(0);
        __builtin_amdgcn_s_barrier();
        __builtin_amdgcn_sched_barrier(0);
        if (s + 2 < 16) { LDX((s + 2) % 3, (s + 2) * 64); LDA((s + 2) % 3, (s + 2) * 64); }
        __builtin_amdgcn_sched_barrier(0);
        const unsigned short* xb  = xs + (s % 3) * (TOKB * 64);
        const unsigned short* abc = ab + (s % 3) * (144 * 64);
        __builtin_amdgcn_s_setprio(1);
#pragma unroll
        for (int ks = 0; ks < 2; ++ks) {
            const int sw = (((ks << 2) | lq) ^ (l15 & 7)) * 8;
            bf16x8 af = *(const bf16x8*)(xb + (m * 16 + l15) * 64 + sw);
#pragma unroll
            for (int j = 0; j < 4; ++j) {
                const int nt = 2 * j + h;
                bf16x8 bf = *(const bf16x8*)(abc + (nt * 16 + l15) * 64 + sw);
                acc[j] = __builtin_amdgcn_mfma_f32_16x16x32_bf16(af, bf, acc[j], 0, 0, 0);
            }
            bf16x8 bl = *(const bf16x8*)(abc + (8 * 16 + l15) * 64 + sw);
            acc[4] = __builtin_amdgcn_mfma_f32_16x16x32_bf16(af, bl, acc[4], 0, 0, 0);
        }
        __builtin_amdgcn_s_setprio(0);
        if (s + 1 < 16) WRX((s + 1) % 3);   // x data for step s+1 (loaded iter s-1)
    }

    // ---- in-register softmax over experts (logits: acc[4], lanes l15<8) ----
    float mx[4], pv[4], sm[4], rt[4];
#pragma unroll
    for (int r = 0; r < 4; ++r) mx[r] = acc[4][r];
#pragma unroll
    for (int msk = 1; msk <= 4; msk <<= 1)
#pragma unroll
        for (int r = 0; r < 4; ++r) mx[r] = fmaxf(mx[r], __shfl_xor(mx[r], msk, 16));
#pragma unroll
    for (int r = 0; r < 4; ++r) { pv[r] = expf(acc[4][r] - mx[r]); sm[r] = pv[r]; }
#pragma unroll
    for (int msk = 1; msk <= 4; msk <<= 1)
#pragma unroll
        for (int r = 0; r < 4; ++r) sm[r] += __shfl_xor(sm[r], msk, 16);
#pragma unroll
    for (int r = 0; r < 4; ++r) rt[r] = SCALE * pv[r] / sm[r];

    __syncthreads();   // xs/ab dead; whs alias becomes live

    // route-weighted wh -> LDS; wave (m,h) supplies experts {h,h+2,h+4,h+6}
#pragma unroll
    for (int j = 0; j < 4; ++j) {
        const int e = 2 * j + h;
        float rb[4];
#pragma unroll
        for (int r = 0; r < 4; ++r) rb[r] = __shfl(rt[r], e, 16);
#pragma unroll
        for (int r = 0; r < 4; ++r)
            whs[(m * 16 + lq * 4 + r) * 140 + e * 16 + l15] = acc[j][r] * rb[r];
    }
    __syncthreads();   // expert exchange between wave pairs

    // GEMM2 A-fragments (group g=h): lane needs expert e = ks*4+lq, r=0..7
    bf16x8 paf[2];   // [ks]
#pragma unroll
    for (int ks = 0; ks < 2; ++ks) {
        const float* hp = whs + (m * 16 + l15) * 140 + ((ks << 2) | lq) * 16 + (h << 3);
        f32x4 v0 = *(const f32x4*)hp;
        f32x4 v1 = *(const f32x4*)(hp + 4);
        uint4 pk;
        pk.x = f2bf(v0[0], v0[1]); pk.y = f2bf(v0[2], v0[3]);
        pk.z = f2bf(v1[0], v1[1]); pk.w = f2bf(v1[2], v1[3]);
        paf[ks] = *(bf16x8*)&pk;
    }
    __syncthreads();   // whs fully consumed; smem reusable as transpose tiles

    // GEMM2 with PIPELINED LDS-transpose epilogue. Wave (m,h): rows m*16..+15,
    // contiguous col span [h*1536, +1536). Double-buffered wave-private tiles:
    // per iteration, store chunk cb-1 (ds_reads wait only prev writes) THEN
    // compute chunk cb (B-loads+MFMA+ds_writes issue while stores drain).
    float* tileA = (float*)smem + (w * 2) * (16 * 132);      // 8 x 8448 B = 67584
    float* tileB = (float*)smem + (w * 2 + 1) * (16 * 132);
    const int erow  = lane >> 5;           // 2 rows per store instr
    const int ec4   = lane & 31;           // 32 float4 = full 128-col chunk
    const int gcolb = h << 11;             // GEMM col base: 0 or 2048
    const int zcolb = 1024 + (h << 9);     // zero col base: 1024 or 1536
    const float4 zf4 = {0.f, 0.f, 0.f, 0.f};

    auto COMPUTE = [&](int cb, float* tp) {   // chunk cb -> tile tp
#pragma unroll
        for (int nn = 0; nn < 8; ++nn) {
            const int n = cb * 8 + nn;
            const unsigned short* bp =
                Bbt + ((size_t)(h << 10) + (n << 4) + l15) * 64 + (lq << 3);
            bf16x8 b0 = *(const bf16x8*)bp;
            bf16x8 b1 = *(const bf16x8*)(bp + 32);
            f32x4 c = {0.f, 0.f, 0.f, 0.f};
            c = __builtin_amdgcn_mfma_f32_16x16x32_bf16(paf[0], b0, c, 0, 0, 0);
            c = __builtin_amdgcn_mfma_f32_16x16x32_bf16(paf[1], b1, c, 0, 0, 0);
#pragma unroll
            for (int r = 0; r < 4; ++r)
                tp[(lq * 4 + r) * 132 + nn * 16 + l15] = c[r];
        }
    };
    auto STORE = [&](int cb, const float* tp) {   // chunk cb GEMM cols + 2 zero rows
#pragma unroll
        for (int j = 0; j < 8; ++j) {
            const int row = j * 2 + erow;
            float4 v = *(const float4*)&tp[row * 132 + ec4 * 4];
            *(float4*)(out + (size_t)(tokb + m * 16 + row) * NOUT
                       + gcolb + cb * 128 + ec4 * 4) = v;
        }
#pragma unroll
        for (int i = 0; i < 4; ++i) {
            const int local = i * 64 + lane;        // 0..255 over [2][128]
            const int row = cb * 2 + (local >> 7);
            const int c4  = local & 127;
            *(float4*)(out + (size_t)(tokb + m * 16 + row) * NOUT
                       + zcolb + c4 * 4) = zf4;
        }
    };

    COMPUTE(0, tileA);
#pragma unroll
    for (int cb = 1; cb < 8; ++cb) {
        float* cur  = (cb & 1) ? tileB : tileA;
        float* prev = (cb & 1) ? tileA : tileB;
        STORE(cb - 1, prev);      // waits (lgkm) only on prev chunk's ds_writes
        COMPUTE(cb, cur);         // issues while prev chunk's stores drain
    }
    STORE(7, tileB);
}

// ---------------------------------------------------------------------------
extern "C" void kernel_launch(void* const* d_in, const int* in_sizes, int n_in,
                              void* d_out, int out_size, void* d_ws, size_t ws_size,
                              hipStream_t stream) {
    const float* x  = (const float*)d_in[0];
    const float* Wr = (const float*)d_in[1];
    const float* A  = (const float*)d_in[2];
    const float* Bw = (const float*)d_in[3];
    unsigned short* Abt = (unsigned short*)((char*)d_ws + WS_ABT);
    unsigned short* Bbt = (unsigned short*)((char*)d_ws + WS_BBT);
    float* out = (float*)d_out;

    k_prep <<<FP + 128, 256, 0, stream>>>(A, Wr, Bw, Abt, Bbt);
    k_fused<<<NTOK / TOKB, 256, 0, stream>>>(x, Abt, Bbt, out);
}

// Round 16
// 62.502 us; speedup vs baseline: 1.2069x; 1.0171x over previous
//
#include <hip/hip_runtime.h>
#include <math.h>

// MoELoRA dims (fixed by the problem)
#define NTOK   16384      // B*S
#define DDIM   1024
#define NE     8
#define NF     128        // E*G*R down-proj features (f = e*16 + g*8 + r)
#define FP     144        // GEMM1 N: 128 h + 8 logits + 8 zero  (9 MFMA N-tiles)
#define ODIM   1024
#define NOUT   3072
#define SCALE  2.0f
#define TOKB   32         // tokens per block -> 512 blocks (4 waves, 2 blocks/CU)

typedef __attribute__((ext_vector_type(8))) short bf16x8;
typedef __attribute__((ext_vector_type(4))) float f32x4;

// ws layout (bytes)
#define WS_ABT 0                        // bf16 [144][1024]   = 294912 B
#define WS_BBT 294912                   // bf16 [2][1024][64] = 262144 B

// pack two fp32 -> (bf16(a) | bf16(b)<<16), round-to-nearest-even
__device__ inline unsigned f2bf(float a, float b) {
    union { float f; unsigned u; } ua, ub;
    ua.f = a; ub.f = b;
    unsigned x = ua.u + (0x7fffu + ((ua.u >> 16) & 1));
    unsigned y = ub.u + (0x7fffu + ((ub.u >> 16) & 1));
    return (x >> 16) | (y & 0xffff0000u);
}

// ---------------------------------------------------------------------------
// Prep: Abt[f][d] = bf16(concat(A, W_route, 0))   (A is already f-major)
//       Bbt[g][o][er] = bf16(Bw[e][g][o][r]), er = e*8+r
__global__ __launch_bounds__(256) void k_prep(const float* __restrict__ A,
                                              const float* __restrict__ Wr,
                                              const float* __restrict__ Bw,
                                              unsigned short* __restrict__ Abt,
                                              unsigned short* __restrict__ Bbt) {
    const int b = blockIdx.x, t = threadIdx.x;
    if (b < FP) {
        const int col = t * 4;
        float4 v = {0.f, 0.f, 0.f, 0.f};
        if (b < NF)           v = *(const float4*)(A + (size_t)b * DDIM + col);
        else if (b < NF + NE) v = *(const float4*)(Wr + (size_t)(b - NF) * DDIM + col);
        uint2 p; p.x = f2bf(v.x, v.y); p.y = f2bf(v.z, v.w);
        *(uint2*)(Abt + (size_t)b * DDIM + col) = p;
    } else {
        const int idx = (b - FP) * 1024 + t * 4;      // over [2][1024][64]
        const int g = idx >> 16, o = (idx >> 6) & 1023, er = idx & 63;
        const int e = er >> 3, r0 = er & 7;           // r0 in {0,4}
        float4 v = *(const float4*)(Bw + ((size_t)(e * 2 + g) * ODIM + o) * 8 + r0);
        uint2 p; p.x = f2bf(v.x, v.y); p.y = f2bf(v.z, v.w);
        *(uint2*)(Bbt + idx) = p;
    }
}

// ---------------------------------------------------------------------------
// Fused, 32-token tiles, 4 waves, 512 blocks (2/CU). Wave (m,h).
//  phase 1: GEMM1 K-loop, 3-deep counted-vmcnt pipeline (no stores).
//  phase 2: in-reg softmax; wh -> LDS; GEMM2 vs L2-hot Bbt; LDS-transpose
//           epilogue; wave h writes contiguous 1536-col span (incl. zeros).
__global__ __launch_bounds__(256) void k_fused(const float* __restrict__ x,
                                               const unsigned short* __restrict__ Abt,
                                               const unsigned short* __restrict__ Bbt,
                                               float* __restrict__ out) {
    __shared__ __align__(16) char smem[67584];
    unsigned short* xs = (unsigned short*)smem;            // [3][32][64] bf16, swizzled
    unsigned short* ab = (unsigned short*)(smem + 12288);  // [3][144][64] bf16, swizzled
    float* whs = (float*)smem;                             // [32][140] fp32 alias (phase 2)

    const int t    = threadIdx.x;
    const int tokb = blockIdx.x * TOKB;
    const int lane = t & 63, w = t >> 6;
    const int m    = w >> 1, h = w & 1;
    const int l15  = lane & 15, lq = lane >> 4;

    f32x4 acc[5];   // 4 expert N-tiles (nt = 2j+h) + logits (tile 8)
#pragma unroll
    for (int n = 0; n < 5; ++n) acc[n] = (f32x4){0.f, 0.f, 0.f, 0.f};

    // x staging: thread covers token t>>3, 8 consecutive floats at (t&7)*8
    const int xtok = t >> 3;
    const int xc   = t & 7;
    float4 xr[3][2];          // 3 in-flight register sets (static indices)

    auto LDX = [&](int set, int k0) {
        xr[set][0] = *(const float4*)(x + (size_t)(tokb + xtok) * DDIM + k0 + xc * 8);
        xr[set][1] = *(const float4*)(x + (size_t)(tokb + xtok) * DDIM + k0 + xc * 8 + 4);
    };
    auto WRX = [&](int j) {   // write xr[j] -> x buffer j (XOR-swizzled)
        unsigned short* xb = xs + j * (TOKB * 64);
        uint4 p;
        p.x = f2bf(xr[j][0].x, xr[j][0].y); p.y = f2bf(xr[j][0].z, xr[j][0].w);
        p.z = f2bf(xr[j][1].x, xr[j][1].y); p.w = f2bf(xr[j][1].z, xr[j][1].w);
        const int c8 = xc ^ (xtok & 7);
        *(uint4*)(xb + xtok * 64 + c8 * 8) = p;
    };
    // A-tile: 18 KB/step via global_load_lds w16; linear LDS dest, source
    // pre-swizzled so content lands XOR-swizzled (rule #21).
    auto LDA = [&](int buf, int k0) {
        unsigned short* base = ab + buf * (144 * 64);
#pragma unroll
        for (int i = 0; i < 5; ++i) {
            if (i < 4 || t < 128) {                // waves 0,1: 5 ops; waves 2,3: 4
                const int c   = i * 256 + t;
                const int row = c >> 3;
                const int c8  = (c & 7) ^ (row & 7);
                const unsigned short* gp = Abt + (size_t)row * DDIM + k0 + c8 * 8;
                unsigned short* lp = base + (i * 256 + w * 64) * 8;  // wave-uniform
                __builtin_amdgcn_global_load_lds(
                    (const __attribute__((address_space(1))) unsigned int*)gp,
                    (__attribute__((address_space(3))) unsigned int*)lp, 16, 0, 0);
            }
        }
    };

    // ---- prologue: steps 0 and 1 in flight; x for step 0 written ----
    LDX(0, 0);   LDA(0, 0);
    LDX(1, 64);  LDA(1, 64);
    WRX(0);

    // ---- K-loop: counted-vmcnt pipeline, prefetch distance 2 ----
    // Per-wave vm ops per step: waves 0,1 = 7 (2 LDX + 5 LDA); waves 2,3 = 6.
    // At iter s, outstanding = steps s,s+1 (minus xr waits); wait leaves
    // exactly step s+1's ops in flight -> step s complete. Buffer safety:
    // step s+2 writes buf (s+2)%3, whose last readers (step s-1) retired
    // before this iteration's barrier.
#pragma unroll 16
    for (int s = 0; s < 16; ++s) {
        if (s == 15)    asm volatile("s_waitcnt vmcnt(0)" ::: "memory");
        else if (w < 2) asm volatile("s_waitcnt vmcnt(7)" ::: "memory");
        else            asm volatile("s_waitcnt vmcnt(6)" ::: "memory");
        asm volatile("s_waitcnt lgkmcnt(0)" ::: "memory");   // WRX visible
        __builtin_amdgcn_sched_barrier(0);
        __builtin_amdgcn_s_barrier();
        __builtin_amdgcn_sched_barrier(0);
        if (s + 2 < 16) { LDX((s + 2) % 3, (s + 2) * 64); LDA((s + 2) % 3, (s + 2) * 64); }
        __builtin_amdgcn_sched_barrier(0);
        const unsigned short* xb  = xs + (s % 3) * (TOKB * 64);
        const unsigned short* abc = ab + (s % 3) * (144 * 64);
        __builtin_amdgcn_s_setprio(1);
#pragma unroll
        for (int ks = 0; ks < 2; ++ks) {
            const int sw = (((ks << 2) | lq) ^ (l15 & 7)) * 8;
            bf16x8 af = *(const bf16x8*)(xb + (m * 16 + l15) * 64 + sw);
#pragma unroll
            for (int j = 0; j < 4; ++j) {
                const int nt = 2 * j + h;
                bf16x8 bf = *(const bf16x8*)(abc + (nt * 16 + l15) * 64 + sw);
                acc[j] = __builtin_amdgcn_mfma_f32_16x16x32_bf16(af, bf, acc[j], 0, 0, 0);
            }
            bf16x8 bl = *(const bf16x8*)(abc + (8 * 16 + l15) * 64 + sw);
            acc[4] = __builtin_amdgcn_mfma_f32_16x16x32_bf16(af, bl, acc[4], 0, 0, 0);
        }
        __builtin_amdgcn_s_setprio(0);
        if (s + 1 < 16) WRX((s + 1) % 3);   // x data for step s+1 (loaded iter s-1)
    }

    // ---- in-register softmax over experts (logits: acc[4], lanes l15<8) ----
    float mx[4], pv[4], sm[4], rt[4];
#pragma unroll
    for (int r = 0; r < 4; ++r) mx[r] = acc[4][r];
#pragma unroll
    for (int msk = 1; msk <= 4; msk <<= 1)
#pragma unroll
        for (int r = 0; r < 4; ++r) mx[r] = fmaxf(mx[r], __shfl_xor(mx[r], msk, 16));
#pragma unroll
    for (int r = 0; r < 4; ++r) { pv[r] = expf(acc[4][r] - mx[r]); sm[r] = pv[r]; }
#pragma unroll
    for (int msk = 1; msk <= 4; msk <<= 1)
#pragma unroll
        for (int r = 0; r < 4; ++r) sm[r] += __shfl_xor(sm[r], msk, 16);
#pragma unroll
    for (int r = 0; r < 4; ++r) rt[r] = SCALE * pv[r] / sm[r];

    __syncthreads();   // xs/ab dead; whs alias becomes live

    // route-weighted wh -> LDS; wave (m,h) supplies experts {h,h+2,h+4,h+6}
#pragma unroll
    for (int j = 0; j < 4; ++j) {
        const int e = 2 * j + h;
        float rb[4];
#pragma unroll
        for (int r = 0; r < 4; ++r) rb[r] = __shfl(rt[r], e, 16);
#pragma unroll
        for (int r = 0; r < 4; ++r)
            whs[(m * 16 + lq * 4 + r) * 140 + e * 16 + l15] = acc[j][r] * rb[r];
    }
    __syncthreads();   // expert exchange between wave pairs

    // GEMM2 A-fragments (group g=h): lane needs expert e = ks*4+lq, r=0..7
    bf16x8 paf[2];   // [ks]
#pragma unroll
    for (int ks = 0; ks < 2; ++ks) {
        const float* hp = whs + (m * 16 + l15) * 140 + ((ks << 2) | lq) * 16 + (h << 3);
        f32x4 v0 = *(const f32x4*)hp;
        f32x4 v1 = *(const f32x4*)(hp + 4);
        uint4 pk;
        pk.x = f2bf(v0[0], v0[1]); pk.y = f2bf(v0[2], v0[3]);
        pk.z = f2bf(v1[0], v1[1]); pk.w = f2bf(v1[2], v1[3]);
        paf[ks] = *(bf16x8*)&pk;
    }
    __syncthreads();   // whs fully consumed; smem reusable as transpose tiles

    // GEMM2 with LDS-transpose epilogue. Wave (m,h) owns rows m*16..+15 and
    // the contiguous col span [h*1536, h*1536+1536):
    //   h=0: GEMM cols [0,1024)   + zeros [1024,1536)
    //   h=1: zeros [1536,2048)    + GEMM cols [2048,3072)
    float* tile = (float*)smem + w * (16 * 132);
    const int erow  = lane >> 5;           // 2 rows per store instr
    const int ec4   = lane & 31;           // 32 float4 = full 128-col chunk
    const int gcolb = h << 11;             // GEMM col base: 0 or 2048
    const int zcolb = 1024 + (h << 9);     // zero col base: 1024 or 1536
    const float4 zf4 = {0.f, 0.f, 0.f, 0.f};
#pragma unroll 1
    for (int cb = 0; cb < 8; ++cb) {
#pragma unroll
        for (int nn = 0; nn < 8; ++nn) {
            const int n = cb * 8 + nn;
            const unsigned short* bp =
                Bbt + ((size_t)(h << 10) + (n << 4) + l15) * 64 + (lq << 3);
            bf16x8 b0 = *(const bf16x8*)bp;
            bf16x8 b1 = *(const bf16x8*)(bp + 32);
            f32x4 c = {0.f, 0.f, 0.f, 0.f};
            c = __builtin_amdgcn_mfma_f32_16x16x32_bf16(paf[0], b0, c, 0, 0, 0);
            c = __builtin_amdgcn_mfma_f32_16x16x32_bf16(paf[1], b1, c, 0, 0, 0);
#pragma unroll
            for (int r = 0; r < 4; ++r)
                tile[(lq * 4 + r) * 132 + nn * 16 + l15] = c[r];
        }
        // wave-private tile: same-wave DS ordering + compiler lgkmcnt waits
#pragma unroll
        for (int j = 0; j < 8; ++j) {
            const int row = j * 2 + erow;
            float4 v = *(const float4*)&tile[row * 132 + ec4 * 4];
            *(float4*)(out + (size_t)(tokb + m * 16 + row) * NOUT
                       + gcolb + cb * 128 + ec4 * 4) = v;
        }
        // 2 full zero rows of the dead middle half (rows cb*2, cb*2+1)
#pragma unroll
        for (int i = 0; i < 4; ++i) {
            const int local = i * 64 + lane;        // 0..255 over [2][128]
            const int row = cb * 2 + (local >> 7);
            const int c4  = local & 127;
            *(float4*)(out + (size_t)(tokb + m * 16 + row) * NOUT
                       + zcolb + c4 * 4) = zf4;
        }
    }
}

// ---------------------------------------------------------------------------
extern "C" void kernel_launch(void* const* d_in, const int* in_sizes, int n_in,
                              void* d_out, int out_size, void* d_ws, size_t ws_size,
                              hipStream_t stream) {
    const float* x  = (const float*)d_in[0];
    const float* Wr = (const float*)d_in[1];
    const float* A  = (const float*)d_in[2];
    const float* Bw = (const float*)d_in[3];
    unsigned short* Abt = (unsigned short*)((char*)d_ws + WS_ABT);
    unsigned short* Bbt = (unsigned short*)((char*)d_ws + WS_BBT);
    float* out = (float*)d_out;

    k_prep <<<FP + 128, 256, 0, stream>>>(A, Wr, Bw, Abt, Bbt);
    k_fused<<<NTOK / TOKB, 256, 0, stream>>>(x, Abt, Bbt, out);
}